// Round 11
// baseline (83.864 us; speedup 1.0000x reference)
//
#include <hip/hip_runtime.h>
#include <math.h>

// Problem constants (from reference): B=16, D=128, T=512.
#define B_DIM 16
#define D_DIM 128
#define T_DIM 512
#define NT4   128        // float4 per T-row
#define CSCALE 8.6316745750453727e-05f   // 1/(512*sqrt(512)) : DC/T * softmax scale
#define REPS  10         // DIAGNOSTIC: repeat identical body; floor=(135-dur)/9

// ---------------------------------------------------------------------------
// DIAGNOSTIC ROUND: exact R3 structure (best known, 13.5us) with the body
// executed REPS times inside one launch. Each rep recomputes identical values
// and rewrites the same output (idempotent -> still correct under re-validate).
// Purpose: (a) separate fixed per-dispatch floor from body time:
//   dur ~= floor + REPS*body;  with R3: floor + body = 13.5
// (b) push dur above the ~40us poison-fills so the kernel finally shows up in
// the top-5 rocprof rows with VALUBusy / FETCH / LDS-conflict / occupancy.
// ---------------------------------------------------------------------------
__global__ __launch_bounds__(512) void fused_attn_kernel(
    const float* __restrict__ queries,
    const float* __restrict__ keys,
    const float* __restrict__ values,
    const float* __restrict__ para,
    const float* __restrict__ para2,
    float* __restrict__ out) {

    int bid = blockIdx.x;
    int b   = bid & 15;
    int i0  = (bid >> 4) * 8;
    int tid = threadIdx.x;
    int wv  = tid >> 6;
    int ln  = tid & 63;

    __shared__ float  s_ksum[D_DIM];
    __shared__ float  s_q[8];
    __shared__ float  s_w[D_DIM][8];        // transposed: [j][row]
    __shared__ float4 s_part[4][8][NT4];    // 64 KB combine buffer

    const float4* k4 = reinterpret_cast<const float4*>(keys)   + (size_t)b * D_DIM * NT4;
    const float4* v4 = reinterpret_cast<const float4*>(values) + (size_t)b * D_DIM * NT4;

    for (int rep = 0; rep < REPS; ++rep) {
        asm volatile("" ::: "memory");   // keep reps from being CSE'd/merged

        // ---- Phase A: ksum for all 128 rows ----
        {
            int rr = ln >> 4;      // row within quad (0..3)
            int cc = ln & 15;      // column chunk (0..15)
            #pragma unroll
            for (int it = 0; it < 4; ++it) {
                int row = it * 32 + wv * 4 + rr;
                const float4* kr = k4 + (size_t)row * NT4;
                float s = 0.f;
                #pragma unroll
                for (int k = 0; k < 8; ++k) {
                    float4 v = kr[cc + k * 16];
                    s += (v.x + v.y) + (v.z + v.w);
                }
                s += __shfl_xor(s, 1, 64);
                s += __shfl_xor(s, 2, 64);
                s += __shfl_xor(s, 4, 64);
                s += __shfl_xor(s, 8, 64);
                if (cc == 0) s_ksum[row] = s;
            }
        }

        // ---- Phase B: qsum of row i0+wv ----
        {
            const float4* qr = reinterpret_cast<const float4*>(queries)
                               + (size_t)(b * D_DIM + i0 + wv) * NT4;
            float4 a = qr[ln];
            float4 d = qr[ln + 64];
            float s = (a.x + a.y) + (a.z + a.w) + (d.x + d.y) + (d.z + d.w);
            #pragma unroll
            for (int off = 32; off > 0; off >>= 1) s += __shfl_xor(s, off, 64);
            if (ln == 0) s_q[wv] = s;
        }
        __syncthreads();

        // ---- Phase C: softmax of row i0+wv (no max-subtract; |logit|<~0.7) ----
        {
            float qc = s_q[wv] * (para[0] * CSCALE);
            const float* p2 = para2 + (size_t)(i0 + wv) * D_DIM;
            float l0 = qc * s_ksum[ln] * p2[ln];
            float l1 = qc * s_ksum[ln + 64] * p2[ln + 64];
            float e0 = __expf(l0);
            float e1 = __expf(l1);
            float s = e0 + e1;
            #pragma unroll
            for (int off = 32; off > 0; off >>= 1) s += __shfl_xor(s, off, 64);
            float inv = 1.0f / s;
            s_w[ln][wv] = e0 * inv;
            s_w[ln + 64][wv] = e1 * inv;
        }
        __syncthreads();

        // ---- Phase D: 4 j-groups x 32 j x 128 t4 ----
        int jq = tid >> 7;        // j-quarter 0..3
        int t4 = tid & 127;       // float4 column
        float4 acc[8];
        #pragma unroll
        for (int r = 0; r < 8; ++r) acc[r] = make_float4(0.f, 0.f, 0.f, 0.f);

        #define FMA4(A, W) \
            A.x += (W) * v.x; A.y += (W) * v.y; A.z += (W) * v.z; A.w += (W) * v.w;

        int jbeg = jq * 32;
        #pragma unroll 8
        for (int j = jbeg; j < jbeg + 32; ++j) {
            float4 v = v4[(size_t)j * NT4 + t4];
            const float4* wp = reinterpret_cast<const float4*>(&s_w[j][0]);
            float4 w0 = wp[0];
            float4 w1 = wp[1];
            FMA4(acc[0], w0.x) FMA4(acc[1], w0.y) FMA4(acc[2], w0.z) FMA4(acc[3], w0.w)
            FMA4(acc[4], w1.x) FMA4(acc[5], w1.y) FMA4(acc[6], w1.z) FMA4(acc[7], w1.w)
        }
        #undef FMA4

        #pragma unroll
        for (int r = 0; r < 8; ++r) s_part[jq][r][t4] = acc[r];
        __syncthreads();

        // combine 4 partials; 1024 float4 outputs, 2 per thread
        float4* out4 = reinterpret_cast<float4*>(out);
        #pragma unroll
        for (int k = 0; k < 2; ++k) {
            int idx = tid + k * 512;
            int r = idx >> 7;
            int tt = idx & 127;
            float4 p0 = s_part[0][r][tt];
            float4 p1 = s_part[1][r][tt];
            float4 p2 = s_part[2][r][tt];
            float4 p3 = s_part[3][r][tt];
            float4 sum;
            sum.x = (p0.x + p1.x) + (p2.x + p3.x);
            sum.y = (p0.y + p1.y) + (p2.y + p3.y);
            sum.z = (p0.z + p1.z) + (p2.z + p3.z);
            sum.w = (p0.w + p1.w) + (p2.w + p3.w);
            out4[(size_t)(b * D_DIM + i0 + r) * NT4 + tt] = sum;
        }
        __syncthreads();   // s_part safe for next rep's phase D
    }
}

extern "C" void kernel_launch(void* const* d_in, const int* in_sizes, int n_in,
                              void* d_out, int out_size, void* d_ws, size_t ws_size,
                              hipStream_t stream) {
    const float* queries = (const float*)d_in[0];  // [B, D, T]
    const float* keys    = (const float*)d_in[1];  // [B, D, T]
    const float* values  = (const float*)d_in[2];  // [B, D, T]
    // d_in[3] = attn_mask (unused)
    const float* para    = (const float*)d_in[4];  // [25]
    const float* para2   = (const float*)d_in[5];  // [D, D]
    float* out = (float*)d_out;                    // [B, D, T] fp32

    fused_attn_kernel<<<B_DIM * (D_DIM / 8), 512, 0, stream>>>(
        queries, keys, values, para, para2, out);
}